// Round 9
// baseline (6294.474 us; speedup 1.0000x reference)
//
#include <hip/hip_runtime.h>
#include <math.h>

#define NEG_SLOPE 0.2f

// ---------------------------------------------------------------- CSR build
__global__ void deg_count_kernel(const int* __restrict__ dst, int* __restrict__ deg, int E){
  int e = blockIdx.x * blockDim.x + threadIdx.x;
  if (e < E) atomicAdd(&deg[dst[e]], 1);
}

__global__ void base_assign_kernel(const int* __restrict__ deg, int* __restrict__ base,
                                   int* __restrict__ counter, int N){
  int n = blockIdx.x * blockDim.x + threadIdx.x;
  if (n < N) base[n] = atomicAdd(counter, deg[n]);
}

__global__ void fill_kernel(const int* __restrict__ ei, const float* __restrict__ ea,
                            const int* __restrict__ base, int* __restrict__ pos,
                            int2* __restrict__ csr_pack, int E){
  int e = blockIdx.x * blockDim.x + threadIdx.x;
  if (e >= E) return;
  int s = ei[e], d = ei[E + e];
  int p = atomicAdd(&pos[d], 1);
  csr_pack[base[d] + p] = make_int2(s, __float_as_int(ea[e]));
}

// ---------------------------------------------------------------- single-wave GEMM
// Block = ONE wave (64 threads) -> no __syncthreads anywhere; LDS is wave-private,
// ordered by lgkmcnt/vmcnt only. grid.y picks W1/W2. 16-row tile per block.
// Lane = (col-group, row-group): CPL col-lanes x RGc row-groups; acc = RPT x 4.
// W streams via register->LDS double buffer: slab s+1 global loads issue before
// compute(s) and stay in flight across it (no barrier to drain them).
// X is read directly from global (broadcast addresses, L1-hot tile) - except
// K=15 where a small padded LDS tile avoids misaligned float4s.
template<int M, int K>
__global__ __launch_bounds__(64, 4) void gemm_skinny_kernel(
    const float* __restrict__ X,
    const float* __restrict__ W1, const float* __restrict__ b1,
    const float* __restrict__ W2, const float* __restrict__ b2,
    float* __restrict__ Y1, float* __restrict__ Y2, int N)
{
  constexpr int TROWS = 16;
  constexpr int CPL   = M / 4;           // col lanes: 32 (M=128) or 16 (M=64)
  constexpr int RGc   = 64 / CPL;        // row groups: 2 or 4
  constexpr int RPT   = TROWS / RGc;     // rows per thread: 8 or 4
  constexpr int SLAB  = 8;
  constexpr int KP    = ((K + SLAB - 1) / SLAB) * SLAB;   // 128 or 16
  constexpr int NS    = KP / SLAB;
  constexpr int WF4   = SLAB * M / 4 / 64;                // 4 (M=128) or 2 (M=64)
  constexpr bool LDSX = (K % 4 != 0);

  __shared__ float ws[2][SLAB * M];
  __shared__ float xsl[LDSX ? TROWS * KP : 1];

  int g    = blockIdx.y;                  // 0 -> W1, 1 -> W2
  const float* W  = g ? W2 : W1;
  const float* bs = g ? b2 : b1;
  float*       Y  = g ? Y2 : Y1;

  int lane = threadIdx.x;
  int cg   = lane % CPL, rg = lane / CPL;
  int col  = cg * 4;
  int r0   = blockIdx.x * TROWS;

  // X base for this thread's rows (rows are in-range: N % TROWS handled by store guard;
  // clamp base so OOB threads read row 0 harmlessly)
  const float* Xb = X + (long)min(r0 + rg * RPT, N - 1) * K;

  // optional LDS X tile (K=15 path), padded to KP for aligned b128 reads
  if constexpr (LDSX){
    #pragma unroll
    for (int i = 0; i < (TROWS * KP + 63) / 64; i++){
      int q = lane + i * 64;
      if (q < TROWS * KP){
        int r = q / KP, c = q % KP;
        int grow = r0 + r;
        xsl[q] = (grow < N && c < K) ? X[(long)grow * K + c] : 0.f;
      }
    }
  }

  float4 wreg[WF4];
  auto loadW = [&](int k0){
    #pragma unroll
    for (int i = 0; i < WF4; i++){
      int q  = lane + i * 64;
      int kk = q / (M / 4), cc = (q % (M / 4)) * 4;
      int k  = k0 + kk;
      float4 v = {0.f,0.f,0.f,0.f};
      if (k < K) v = *(const float4*)(W + (long)k * M + cc);
      wreg[i] = v;
    }
  };
  auto storeW = [&](int b){
    #pragma unroll
    for (int i = 0; i < WF4; i++)
      *(float4*)&ws[b][(lane + i * 64) * 4] = wreg[i];
  };

  float acc[RPT][4];
  #pragma unroll
  for (int i = 0; i < RPT; i++){
    acc[i][0] = 0.f; acc[i][1] = 0.f; acc[i][2] = 0.f; acc[i][3] = 0.f;
  }

  loadW(0);
  storeW(0);

  for (int s = 0; s < NS; s++){
    int b = s & 1;
    if (s + 1 < NS) loadW((s + 1) * SLAB);     // global loads overlap compute below
    #pragma unroll
    for (int kb = 0; kb < SLAB; kb += 4){
      int kk = s * SLAB + kb;
      float4 xv[RPT];
      #pragma unroll
      for (int i = 0; i < RPT; i++){
        if constexpr (LDSX)
          xv[i] = *(const float4*)&xsl[(rg * RPT + i) * KP + kk];
        else
          xv[i] = *(const float4*)(Xb + i * K + kk);   // broadcast across col lanes
      }
      #pragma unroll
      for (int t = 0; t < 4; t++){
        float4 w4 = *(const float4*)&ws[b][(kb + t) * M + col];
        #pragma unroll
        for (int i = 0; i < RPT; i++){
          float a = (t == 0) ? xv[i].x : (t == 1) ? xv[i].y : (t == 2) ? xv[i].z : xv[i].w;
          acc[i][0] = fmaf(a, w4.x, acc[i][0]);
          acc[i][1] = fmaf(a, w4.y, acc[i][1]);
          acc[i][2] = fmaf(a, w4.z, acc[i][2]);
          acc[i][3] = fmaf(a, w4.w, acc[i][3]);
        }
      }
    }
    if (s + 1 < NS) storeW(1 - b);             // waits its own vmcnt; no cross-wave barrier
  }

  float4 bv = *(const float4*)&bs[col];
  #pragma unroll
  for (int i = 0; i < RPT; i++){
    int row = r0 + rg * RPT + i;
    if (row < N){
      float4 o = make_float4(acc[i][0]+bv.x, acc[i][1]+bv.y, acc[i][2]+bv.z, acc[i][3]+bv.w);
      *(float4*)&Y[(long)row * M + col] = o;
    }
  }
}

// ---------------------------------------------------------------- fused edge softmax + aggregation
// (unchanged from R5/R8 agg) One wave per dst node, lane owns 8 contiguous channels,
// contiguous row reads, 32-bit saddr offsets, no-max softmax, optional fused linear.
template<int C>
__global__ __launch_bounds__(512) void agg_kernel(
    const float* __restrict__ xl, const float* __restrict__ xr,
    const int* __restrict__ base, const int* __restrict__ deg,
    const int2* __restrict__ csr_pack,
    const float* __restrict__ We, const float* __restrict__ att,
    const float* __restrict__ bias, float* __restrict__ hout,
    const float* __restrict__ Wlin, const float* __restrict__ blin,
    float* __restrict__ outF, int N, int do_elu)
{
  constexpr int HC  = 8 * C;
  constexpr int LPE = HC / 8;
  constexpr int ES  = 64 / LPE;
  constexpr int NP  = (LPE == 16) ? 4 : 2;
  constexpr int B   = ES * NP;
  constexpr int SH  = (HC == 128) ? 9 : 8;
  constexpr int HR  = C / 8;

  int lane = threadIdx.x & 63;
  int wv   = blockIdx.x * (blockDim.x >> 6) + (threadIdx.x >> 6);
  int nwv  = gridDim.x * (blockDim.x >> 6);
  int slot = lane / LPE;
  int hl   = lane % LPE;
  unsigned cb = (unsigned)hl * 32u;

  const char* xlb = (const char*)xl;
  const char* xrb = (const char*)xr;

  float4 attA = *(const float4*)((const char*)att + cb);
  float4 attB = *(const float4*)((const char*)att + cb + 16);
  float4 weA  = *(const float4*)((const char*)We  + cb);
  float4 weB  = *(const float4*)((const char*)We  + cb + 16);

  for (int n = wv; n < N; n += nwv){
    unsigned nb = ((unsigned)n << SH) + cb;
    float4 xrA = *(const float4*)(xrb + nb);
    float4 xrB = *(const float4*)(xrb + nb + 16);
    float4 accA = {0.f,0.f,0.f,0.f}, accB = {0.f,0.f,0.f,0.f};
    float lrun = 0.f;
    int s0 = base[n], end = s0 + deg[n];

    for (int s = s0; s < end; s += B){
      int2 pk[NP]; bool val[NP];
      #pragma unroll
      for (int t = 0; t < NP; t++){
        int idx = s + t * ES + slot;
        val[t] = idx < end;
        pk[t]  = csr_pack[val[t] ? idx : s0];
      }
      float4 rA[NP], rB[NP];
      #pragma unroll
      for (int t = 0; t < NP; t++){
        unsigned ro = ((unsigned)pk[t].x << SH) + cb;
        rA[t] = *(const float4*)(xlb + ro);
        rB[t] = *(const float4*)(xlb + ro + 16);
      }
      #pragma unroll
      for (int t = 0; t < NP; t++){
        float eav = __int_as_float(pk[t].y);
        float t0 = rA[t].x + xrA.x + eav * weA.x;
        float t1 = rA[t].y + xrA.y + eav * weA.y;
        float t2 = rA[t].z + xrA.z + eav * weA.z;
        float t3 = rA[t].w + xrA.w + eav * weA.w;
        float t4 = rB[t].x + xrB.x + eav * weB.x;
        float t5 = rB[t].y + xrB.y + eav * weB.y;
        float t6 = rB[t].z + xrB.z + eav * weB.z;
        float t7 = rB[t].w + xrB.w + eav * weB.w;
        float m0 = fmaxf(t0,0.f) + NEG_SLOPE * fminf(t0,0.f);
        float m1 = fmaxf(t1,0.f) + NEG_SLOPE * fminf(t1,0.f);
        float m2 = fmaxf(t2,0.f) + NEG_SLOPE * fminf(t2,0.f);
        float m3 = fmaxf(t3,0.f) + NEG_SLOPE * fminf(t3,0.f);
        float m4 = fmaxf(t4,0.f) + NEG_SLOPE * fminf(t4,0.f);
        float m5 = fmaxf(t5,0.f) + NEG_SLOPE * fminf(t5,0.f);
        float m6 = fmaxf(t6,0.f) + NEG_SLOPE * fminf(t6,0.f);
        float m7 = fmaxf(t7,0.f) + NEG_SLOPE * fminf(t7,0.f);
        float p = ((m0*attA.x + m1*attA.y) + (m2*attA.z + m3*attA.w))
                + ((m4*attB.x + m5*attB.y) + (m6*attB.z + m7*attB.w));
        #pragma unroll
        for (int o = 1; o < HR; o <<= 1) p += __shfl_xor(p, o);
        float pe = val[t] ? __expf(p) : 0.f;
        lrun += pe;
        accA.x += pe * rA[t].x; accA.y += pe * rA[t].y;
        accA.z += pe * rA[t].z; accA.w += pe * rA[t].w;
        accB.x += pe * rB[t].x; accB.y += pe * rB[t].y;
        accB.z += pe * rB[t].z; accB.w += pe * rB[t].w;
      }
    }
    #pragma unroll
    for (int o = LPE; o < 64; o <<= 1){
      lrun  += __shfl_xor(lrun, o);
      accA.x += __shfl_xor(accA.x, o); accA.y += __shfl_xor(accA.y, o);
      accA.z += __shfl_xor(accA.z, o); accA.w += __shfl_xor(accA.w, o);
      accB.x += __shfl_xor(accB.x, o); accB.y += __shfl_xor(accB.y, o);
      accB.z += __shfl_xor(accB.z, o); accB.w += __shfl_xor(accB.w, o);
    }
    float inv = 1.f / (lrun + 1e-16f);
    float4 bA = *(const float4*)((const char*)bias + cb);
    float4 bB = *(const float4*)((const char*)bias + cb + 16);
    float4 oA, oB;
    oA.x = accA.x * inv + bA.x; oA.y = accA.y * inv + bA.y;
    oA.z = accA.z * inv + bA.z; oA.w = accA.w * inv + bA.w;
    oB.x = accB.x * inv + bB.x; oB.y = accB.y * inv + bB.y;
    oB.z = accB.z * inv + bB.z; oB.w = accB.w * inv + bB.w;
    if (do_elu){
      oA.x = oA.x > 0.f ? oA.x : (__expf(oA.x) - 1.f);
      oA.y = oA.y > 0.f ? oA.y : (__expf(oA.y) - 1.f);
      oA.z = oA.z > 0.f ? oA.z : (__expf(oA.z) - 1.f);
      oA.w = oA.w > 0.f ? oA.w : (__expf(oA.w) - 1.f);
      oB.x = oB.x > 0.f ? oB.x : (__expf(oB.x) - 1.f);
      oB.y = oB.y > 0.f ? oB.y : (__expf(oB.y) - 1.f);
      oB.z = oB.z > 0.f ? oB.z : (__expf(oB.z) - 1.f);
      oB.w = oB.w > 0.f ? oB.w : (__expf(oB.w) - 1.f);
    }
    if (outF){
      float4 wA = *(const float4*)((const char*)Wlin + cb);
      float4 wB = *(const float4*)((const char*)Wlin + cb + 16);
      float v = ((oA.x*wA.x + oA.y*wA.y) + (oA.z*wA.z + oA.w*wA.w))
              + ((oB.x*wB.x + oB.y*wB.y) + (oB.z*wB.z + oB.w*wB.w));
      #pragma unroll
      for (int o = 1; o < LPE; o <<= 1) v += __shfl_xor(v, o);
      if (lane == 0) outF[n] = v + blin[0];
    } else if (slot == 0){
      char* hb = (char*)hout + (((unsigned)n << SH) + cb);
      *(float4*)hb = oA;
      *(float4*)(hb + 16) = oB;
    }
  }
}

// ----------------------------------------------------------------
extern "C" void kernel_launch(void* const* d_in, const int* in_sizes, int n_in,
                              void* d_out, int out_size, void* d_ws, size_t ws_size,
                              hipStream_t stream)
{
  const float* x  = (const float*)d_in[0];
  const float* ea = (const float*)d_in[1];
  const int*   ei = (const int*)d_in[2];
  const int N = in_sizes[0] / 15;
  const int E = in_sizes[1];

  const float* P[28];
  for (int i = 0; i < 28; i++) P[i] = (const float*)d_in[3 + i];
  const float* Wlin = (const float*)d_in[31];
  const float* blin = (const float*)d_in[32];

  size_t off = 0;
  auto carve = [&](size_t bytes) -> char* {
    char* p = (char*)d_ws + off;
    off = (off + bytes + 255) & ~(size_t)255;
    return p;
  };
  int*   meta     = (int*)  carve(sizeof(int)  * (size_t)(3 * N + 64));
  int*   deg      = meta;                // [N] zeroed
  int*   pos      = meta + N;            // [N] zeroed
  int*   base     = meta + 2 * N;        // [N]
  int*   counter  = meta + 3 * N;        // [1] zeroed
  int2*  csr_pack = (int2*) carve(sizeof(int2) * (size_t)E);
  float* xl       = (float*)carve(sizeof(float) * (size_t)N * 128);
  float* xr       = (float*)carve(sizeof(float) * (size_t)N * 128);
  float* hA       = (float*)carve(sizeof(float) * (size_t)N * 128);
  float* hB       = (float*)carve(sizeof(float) * (size_t)N * 128);

  hipMemsetAsync(deg,     0, sizeof(int) * (size_t)(2 * N), stream);
  hipMemsetAsync(counter, 0, sizeof(int), stream);

  int eb = (E + 255) / 256;
  int nb = (N + 255) / 256;
  deg_count_kernel  <<<eb, 256, 0, stream>>>(ei + E, deg, E);
  base_assign_kernel<<<nb, 256, 0, stream>>>(deg, base, counter, N);
  fill_kernel       <<<eb, 256, 0, stream>>>(ei, ea, base, pos, csr_pack, E);

  dim3 ggrid((N + 15) / 16, 2);   // 16-row tiles, grid.y = W1/W2
  int agrid = 2048;               // agg: grid-stride, 8 waves/block

  // layer 1: din=15, H*C=128, ELU
  gemm_skinny_kernel<128, 15><<<ggrid, 64, 0, stream>>>(x, P[0], P[1], P[2], P[3], xl, xr, N);
  agg_kernel<16><<<agrid, 512, 0, stream>>>(xl, xr, base, deg, csr_pack, P[4], P[5], P[6], hA,
                                            nullptr, nullptr, nullptr, N, 1);
  // layer 2: din=128, ELU
  gemm_skinny_kernel<128, 128><<<ggrid, 64, 0, stream>>>(hA, P[7], P[8], P[9], P[10], xl, xr, N);
  agg_kernel<16><<<agrid, 512, 0, stream>>>(xl, xr, base, deg, csr_pack, P[11], P[12], P[13], hB,
                                            nullptr, nullptr, nullptr, N, 1);
  // layer 3: din=128, ELU
  gemm_skinny_kernel<128, 128><<<ggrid, 64, 0, stream>>>(hB, P[14], P[15], P[16], P[17], xl, xr, N);
  agg_kernel<16><<<agrid, 512, 0, stream>>>(xl, xr, base, deg, csr_pack, P[18], P[19], P[20], hA,
                                            nullptr, nullptr, nullptr, N, 1);
  // layer 4: din=128, H*C=64, no ELU + fused final linear 64->1
  gemm_skinny_kernel<64, 128><<<ggrid, 64, 0, stream>>>(hA, P[21], P[22], P[23], P[24], xl, xr, N);
  agg_kernel<8><<<agrid, 512, 0, stream>>>(xl, xr, base, deg, csr_pack, P[25], P[26], P[27], hB,
                                           Wlin, blin, (float*)d_out, N, 0);
}

// Round 10
// 658.254 us; speedup vs baseline: 9.5624x; 9.5624x over previous
//
#include <hip/hip_runtime.h>
#include <math.h>

#define NEG_SLOPE 0.2f

// ---------------------------------------------------------------- CSR build
__global__ void deg_count_kernel(const int* __restrict__ dst, int* __restrict__ deg, int E){
  int e = blockIdx.x * blockDim.x + threadIdx.x;
  if (e < E) atomicAdd(&deg[dst[e]], 1);
}

__global__ void base_assign_kernel(const int* __restrict__ deg, int* __restrict__ base,
                                   int* __restrict__ counter, int N){
  int n = blockIdx.x * blockDim.x + threadIdx.x;
  if (n < N) base[n] = atomicAdd(counter, deg[n]);
}

__global__ void fill_kernel(const int* __restrict__ ei, const float* __restrict__ ea,
                            const int* __restrict__ base, int* __restrict__ pos,
                            int2* __restrict__ csr_pack, int E){
  int e = blockIdx.x * blockDim.x + threadIdx.x;
  if (e >= E) return;
  int s = ei[e], d = ei[E + e];
  int p = atomicAdd(&pos[d], 1);
  csr_pack[base[d] + p] = make_int2(s, __float_as_int(ea[e]));
}

// ---------------------------------------------------------------- dual GEMM, 8x8 thread tile
// (exact R4 structure — measured 70 us per K=128 dual dispatch, the best of all
// 6 GEMM variants tried; barrier-per-slab, single-buffered, no prefetch).
template<int M, int K>
__global__ __launch_bounds__(128) void gemm_dual_kernel(
    const float* __restrict__ X,
    const float* __restrict__ W1, const float* __restrict__ b1,
    const float* __restrict__ W2, const float* __restrict__ b2,
    float* __restrict__ Y1, float* __restrict__ Y2, int N)
{
  constexpr int CG   = M / 4;          // col groups: 32 (M=128) or 16 (M=64)
  constexpr int RG   = 128 / CG;       // row groups: 4 or 8
  constexpr int TR   = RG * 8;         // rows per block: 32 or 64
  constexpr int SLAB = 16;
  __shared__ float xs [TR * SLAB];
  __shared__ float ws1[SLAB * M];
  __shared__ float ws2[SLAB * M];

  int tid = threadIdx.x;
  int r0  = blockIdx.x * TR;
  int cg  = tid % CG, rg = tid / CG;
  int col = cg * 4;

  float acc1[8][4], acc2[8][4];
  #pragma unroll
  for (int i = 0; i < 8; i++)
    #pragma unroll
    for (int j = 0; j < 4; j++){ acc1[i][j] = 0.f; acc2[i][j] = 0.f; }

  for (int k0 = 0; k0 < K; k0 += SLAB){
    if (k0) __syncthreads();
    constexpr int CH = SLAB / 4;
    for (int q = tid; q < TR * CH; q += 128){
      int r = q / CH, ch = (q % CH) * 4;
      int grow = r0 + r, kg = k0 + ch;
      float4 v = {0.f,0.f,0.f,0.f};
      if (grow < N){
        if constexpr (K % 4 == 0){
          v = *(const float4*)(X + (long)grow * K + kg);
        } else {
          const float* px = X + (long)grow * K;
          if (kg + 0 < K) v.x = px[kg + 0];
          if (kg + 1 < K) v.y = px[kg + 1];
          if (kg + 2 < K) v.z = px[kg + 2];
          if (kg + 3 < K) v.w = px[kg + 3];
        }
      }
      *(float4*)&xs[r * SLAB + ch] = v;
    }
    for (int q = tid; q < SLAB * M / 4; q += 128){
      int kk = q / (M / 4), cc = (q % (M / 4)) * 4;
      int k = k0 + kk;
      float4 v1 = {0.f,0.f,0.f,0.f}, v2 = {0.f,0.f,0.f,0.f};
      if (k < K){
        v1 = *(const float4*)(W1 + (long)k * M + cc);
        v2 = *(const float4*)(W2 + (long)k * M + cc);
      }
      *(float4*)&ws1[kk * M + cc] = v1;
      *(float4*)&ws2[kk * M + cc] = v2;
    }
    __syncthreads();
    #pragma unroll
    for (int kb = 0; kb < SLAB; kb += 4){
      float4 xv[8];
      #pragma unroll
      for (int i = 0; i < 8; i++)
        xv[i] = *(const float4*)&xs[(rg * 8 + i) * SLAB + kb];
      #pragma unroll
      for (int t = 0; t < 4; t++){
        float4 u1 = *(const float4*)&ws1[(kb + t) * M + col];
        float4 u2 = *(const float4*)&ws2[(kb + t) * M + col];
        #pragma unroll
        for (int i = 0; i < 8; i++){
          float a = (t == 0) ? xv[i].x : (t == 1) ? xv[i].y : (t == 2) ? xv[i].z : xv[i].w;
          acc1[i][0] += a * u1.x; acc1[i][1] += a * u1.y;
          acc1[i][2] += a * u1.z; acc1[i][3] += a * u1.w;
          acc2[i][0] += a * u2.x; acc2[i][1] += a * u2.y;
          acc2[i][2] += a * u2.z; acc2[i][3] += a * u2.w;
        }
      }
    }
  }
  float4 bv1 = *(const float4*)&b1[col];
  float4 bv2 = *(const float4*)&b2[col];
  #pragma unroll
  for (int i = 0; i < 8; i++){
    int row = r0 + rg * 8 + i;
    if (row < N){
      float4 o1 = make_float4(acc1[i][0]+bv1.x, acc1[i][1]+bv1.y, acc1[i][2]+bv1.z, acc1[i][3]+bv1.w);
      float4 o2 = make_float4(acc2[i][0]+bv2.x, acc2[i][1]+bv2.y, acc2[i][2]+bv2.z, acc2[i][3]+bv2.w);
      *(float4*)&Y1[(long)row * M + col] = o1;
      *(float4*)&Y2[(long)row * M + col] = o2;
    }
  }
}

// ---------------------------------------------------------------- fused edge softmax + aggregation
// (exact R6 structure) One wave per dst node, lane owns 8 contiguous channels,
// contiguous row reads, 32-bit saddr offsets, no-max softmax, optional fused linear.
template<int C>
__global__ __launch_bounds__(512) void agg_kernel(
    const float* __restrict__ xl, const float* __restrict__ xr,
    const int* __restrict__ base, const int* __restrict__ deg,
    const int2* __restrict__ csr_pack,
    const float* __restrict__ We, const float* __restrict__ att,
    const float* __restrict__ bias, float* __restrict__ hout,
    const float* __restrict__ Wlin, const float* __restrict__ blin,
    float* __restrict__ outF, int N, int do_elu)
{
  constexpr int HC  = 8 * C;
  constexpr int LPE = HC / 8;
  constexpr int ES  = 64 / LPE;
  constexpr int NP  = (LPE == 16) ? 4 : 2;
  constexpr int B   = ES * NP;
  constexpr int SH  = (HC == 128) ? 9 : 8;
  constexpr int HR  = C / 8;

  int lane = threadIdx.x & 63;
  int wv   = blockIdx.x * (blockDim.x >> 6) + (threadIdx.x >> 6);
  int nwv  = gridDim.x * (blockDim.x >> 6);
  int slot = lane / LPE;
  int hl   = lane % LPE;
  unsigned cb = (unsigned)hl * 32u;

  const char* xlb = (const char*)xl;
  const char* xrb = (const char*)xr;

  float4 attA = *(const float4*)((const char*)att + cb);
  float4 attB = *(const float4*)((const char*)att + cb + 16);
  float4 weA  = *(const float4*)((const char*)We  + cb);
  float4 weB  = *(const float4*)((const char*)We  + cb + 16);

  for (int n = wv; n < N; n += nwv){
    unsigned nb = ((unsigned)n << SH) + cb;
    float4 xrA = *(const float4*)(xrb + nb);
    float4 xrB = *(const float4*)(xrb + nb + 16);
    float4 accA = {0.f,0.f,0.f,0.f}, accB = {0.f,0.f,0.f,0.f};
    float lrun = 0.f;
    int s0 = base[n], end = s0 + deg[n];

    for (int s = s0; s < end; s += B){
      int2 pk[NP]; bool val[NP];
      #pragma unroll
      for (int t = 0; t < NP; t++){
        int idx = s + t * ES + slot;
        val[t] = idx < end;
        pk[t]  = csr_pack[val[t] ? idx : s0];
      }
      float4 rA[NP], rB[NP];
      #pragma unroll
      for (int t = 0; t < NP; t++){
        unsigned ro = ((unsigned)pk[t].x << SH) + cb;
        rA[t] = *(const float4*)(xlb + ro);
        rB[t] = *(const float4*)(xlb + ro + 16);
      }
      #pragma unroll
      for (int t = 0; t < NP; t++){
        float eav = __int_as_float(pk[t].y);
        float t0 = rA[t].x + xrA.x + eav * weA.x;
        float t1 = rA[t].y + xrA.y + eav * weA.y;
        float t2 = rA[t].z + xrA.z + eav * weA.z;
        float t3 = rA[t].w + xrA.w + eav * weA.w;
        float t4 = rB[t].x + xrB.x + eav * weB.x;
        float t5 = rB[t].y + xrB.y + eav * weB.y;
        float t6 = rB[t].z + xrB.z + eav * weB.z;
        float t7 = rB[t].w + xrB.w + eav * weB.w;
        float m0 = fmaxf(t0,0.f) + NEG_SLOPE * fminf(t0,0.f);
        float m1 = fmaxf(t1,0.f) + NEG_SLOPE * fminf(t1,0.f);
        float m2 = fmaxf(t2,0.f) + NEG_SLOPE * fminf(t2,0.f);
        float m3 = fmaxf(t3,0.f) + NEG_SLOPE * fminf(t3,0.f);
        float m4 = fmaxf(t4,0.f) + NEG_SLOPE * fminf(t4,0.f);
        float m5 = fmaxf(t5,0.f) + NEG_SLOPE * fminf(t5,0.f);
        float m6 = fmaxf(t6,0.f) + NEG_SLOPE * fminf(t6,0.f);
        float m7 = fmaxf(t7,0.f) + NEG_SLOPE * fminf(t7,0.f);
        float p = ((m0*attA.x + m1*attA.y) + (m2*attA.z + m3*attA.w))
                + ((m4*attB.x + m5*attB.y) + (m6*attB.z + m7*attB.w));
        #pragma unroll
        for (int o = 1; o < HR; o <<= 1) p += __shfl_xor(p, o);
        float pe = val[t] ? __expf(p) : 0.f;
        lrun += pe;
        accA.x += pe * rA[t].x; accA.y += pe * rA[t].y;
        accA.z += pe * rA[t].z; accA.w += pe * rA[t].w;
        accB.x += pe * rB[t].x; accB.y += pe * rB[t].y;
        accB.z += pe * rB[t].z; accB.w += pe * rB[t].w;
      }
    }
    #pragma unroll
    for (int o = LPE; o < 64; o <<= 1){
      lrun  += __shfl_xor(lrun, o);
      accA.x += __shfl_xor(accA.x, o); accA.y += __shfl_xor(accA.y, o);
      accA.z += __shfl_xor(accA.z, o); accA.w += __shfl_xor(accA.w, o);
      accB.x += __shfl_xor(accB.x, o); accB.y += __shfl_xor(accB.y, o);
      accB.z += __shfl_xor(accB.z, o); accB.w += __shfl_xor(accB.w, o);
    }
    float inv = 1.f / (lrun + 1e-16f);
    float4 bA = *(const float4*)((const char*)bias + cb);
    float4 bB = *(const float4*)((const char*)bias + cb + 16);
    float4 oA, oB;
    oA.x = accA.x * inv + bA.x; oA.y = accA.y * inv + bA.y;
    oA.z = accA.z * inv + bA.z; oA.w = accA.w * inv + bA.w;
    oB.x = accB.x * inv + bB.x; oB.y = accB.y * inv + bB.y;
    oB.z = accB.z * inv + bB.z; oB.w = accB.w * inv + bB.w;
    if (do_elu){
      oA.x = oA.x > 0.f ? oA.x : (__expf(oA.x) - 1.f);
      oA.y = oA.y > 0.f ? oA.y : (__expf(oA.y) - 1.f);
      oA.z = oA.z > 0.f ? oA.z : (__expf(oA.z) - 1.f);
      oA.w = oA.w > 0.f ? oA.w : (__expf(oA.w) - 1.f);
      oB.x = oB.x > 0.f ? oB.x : (__expf(oB.x) - 1.f);
      oB.y = oB.y > 0.f ? oB.y : (__expf(oB.y) - 1.f);
      oB.z = oB.z > 0.f ? oB.z : (__expf(oB.z) - 1.f);
      oB.w = oB.w > 0.f ? oB.w : (__expf(oB.w) - 1.f);
    }
    if (outF){
      float4 wA = *(const float4*)((const char*)Wlin + cb);
      float4 wB = *(const float4*)((const char*)Wlin + cb + 16);
      float v = ((oA.x*wA.x + oA.y*wA.y) + (oA.z*wA.z + oA.w*wA.w))
              + ((oB.x*wB.x + oB.y*wB.y) + (oB.z*wB.z + oB.w*wB.w));
      #pragma unroll
      for (int o = 1; o < LPE; o <<= 1) v += __shfl_xor(v, o);
      if (lane == 0) outF[n] = v + blin[0];
    } else if (slot == 0){
      char* hb = (char*)hout + (((unsigned)n << SH) + cb);
      *(float4*)hb = oA;
      *(float4*)(hb + 16) = oB;
    }
  }
}

// ----------------------------------------------------------------
extern "C" void kernel_launch(void* const* d_in, const int* in_sizes, int n_in,
                              void* d_out, int out_size, void* d_ws, size_t ws_size,
                              hipStream_t stream)
{
  const float* x  = (const float*)d_in[0];
  const float* ea = (const float*)d_in[1];
  const int*   ei = (const int*)d_in[2];
  const int N = in_sizes[0] / 15;
  const int E = in_sizes[1];

  const float* P[28];
  for (int i = 0; i < 28; i++) P[i] = (const float*)d_in[3 + i];
  const float* Wlin = (const float*)d_in[31];
  const float* blin = (const float*)d_in[32];

  size_t off = 0;
  auto carve = [&](size_t bytes) -> char* {
    char* p = (char*)d_ws + off;
    off = (off + bytes + 255) & ~(size_t)255;
    return p;
  };
  int*   meta     = (int*)  carve(sizeof(int)  * (size_t)(3 * N + 64));
  int*   deg      = meta;                // [N] zeroed
  int*   pos      = meta + N;            // [N] zeroed
  int*   base     = meta + 2 * N;        // [N]
  int*   counter  = meta + 3 * N;        // [1] zeroed
  int2*  csr_pack = (int2*) carve(sizeof(int2) * (size_t)E);
  float* xl       = (float*)carve(sizeof(float) * (size_t)N * 128);
  float* xr       = (float*)carve(sizeof(float) * (size_t)N * 128);
  float* hA       = (float*)carve(sizeof(float) * (size_t)N * 128);
  float* hB       = (float*)carve(sizeof(float) * (size_t)N * 128);

  hipMemsetAsync(deg,     0, sizeof(int) * (size_t)(2 * N), stream);
  hipMemsetAsync(counter, 0, sizeof(int), stream);

  int eb = (E + 255) / 256;
  int nb = (N + 255) / 256;
  deg_count_kernel  <<<eb, 256, 0, stream>>>(ei + E, deg, E);
  base_assign_kernel<<<nb, 256, 0, stream>>>(deg, base, counter, N);
  fill_kernel       <<<eb, 256, 0, stream>>>(ei, ea, base, pos, csr_pack, E);

  int g128 = (N + 31) / 32;   // M=128: 32-row tiles, 128 threads
  int g64  = (N + 63) / 64;   // M=64:  64-row tiles, 128 threads
  int agrid = 2048;           // agg: grid-stride, 8 waves/block

  // layer 1: din=15, H*C=128, ELU
  gemm_dual_kernel<128, 15><<<g128, 128, 0, stream>>>(x, P[0], P[1], P[2], P[3], xl, xr, N);
  agg_kernel<16><<<agrid, 512, 0, stream>>>(xl, xr, base, deg, csr_pack, P[4], P[5], P[6], hA,
                                            nullptr, nullptr, nullptr, N, 1);
  // layer 2: din=128, ELU
  gemm_dual_kernel<128, 128><<<g128, 128, 0, stream>>>(hA, P[7], P[8], P[9], P[10], xl, xr, N);
  agg_kernel<16><<<agrid, 512, 0, stream>>>(xl, xr, base, deg, csr_pack, P[11], P[12], P[13], hB,
                                            nullptr, nullptr, nullptr, N, 1);
  // layer 3: din=128, ELU
  gemm_dual_kernel<128, 128><<<g128, 128, 0, stream>>>(hB, P[14], P[15], P[16], P[17], xl, xr, N);
  agg_kernel<16><<<agrid, 512, 0, stream>>>(xl, xr, base, deg, csr_pack, P[18], P[19], P[20], hA,
                                            nullptr, nullptr, nullptr, N, 1);
  // layer 4: din=128, H*C=64, no ELU + fused final linear 64->1
  gemm_dual_kernel<64, 128><<<g64, 128, 0, stream>>>(hA, P[21], P[22], P[23], P[24], xl, xr, N);
  agg_kernel<8><<<agrid, 512, 0, stream>>>(xl, xr, base, deg, csr_pack, P[25], P[26], P[27], hB,
                                           Wlin, blin, (float*)d_out, N, 0);
}